// Round 1
// 386.066 us; speedup vs baseline: 1.0223x; 1.0223x over previous
//
#include <hip/hip_runtime.h>

typedef unsigned short u16;
typedef unsigned int u32;

typedef __bf16 bf16x8 __attribute__((ext_vector_type(8)));
typedef unsigned short ushort8 __attribute__((ext_vector_type(8)));
typedef float f32x16 __attribute__((ext_vector_type(16)));

// workspace offsets (in floats)
#define STATSP 2048     // 16*12*64*2 = 24576 floats of stats partials
#define EPOFF 32768     // 3*96*256 = 73728 u32: packed (hi|lo<<16) bf16 of E[s][t][o]
#define KKOFF0 591872
#define KKOFF1 616448
#define KKOFF2 665600
#define WOFF 763904
#define R0OFF 5482496
#define R1OFF 6072320
#define R2OFF 7251968
#define HTOTOFF 11675648
// total = 11712512 floats = ~46.9 MB
// fp64 chain scratch lives INSIDE the Wtil region [WOFF, R0OFF); it is fully
// consumed before k_s3 overwrites Wtil. Offsets in doubles relative to
// (double*)(ws + WOFF):
#define AD64 0        // 3*65536 doubles  (Ad fp64, per scale)
#define PD64 196608   // 6*65536 doubles  (P ping-pong, per scale)
#define KKD64 589824  // 672*256 doubles  (KK rows: s0 96, s1 192, s2 384)

// float -> packed u32: low16 = bf16 RNE of a, high16 = bf16 (trunc) of residual
__device__ __forceinline__ u32 pack_hl(float a) {
  u32 bits = __builtin_bit_cast(u32, a);
  u32 hi = (bits + 0x7fffu + ((bits >> 16) & 1u)) >> 16;
  float hif = __builtin_bit_cast(float, hi << 16);
  float r = a - hif;
  u32 lo = __builtin_bit_cast(u32, r) >> 16;
  return hi | (lo << 16);
}

__device__ __forceinline__ void unpk8(const u32* p, bf16x8& h, bf16x8& l) {
  ushort8 hu, lu;
#pragma unroll
  for (int j = 0; j < 8; ++j) {
    u32 v = p[j];
    hu[j] = (unsigned short)(v & 0xffffu);
    lu[j] = (unsigned short)(v >> 16);
  }
  h = __builtin_bit_cast(bf16x8, hu);
  l = __builtin_bit_cast(bf16x8, lu);
}

// ---- k_pre: A->fp64, seed KK row0, stats1, zero Htot, pack E hi/lo ----
__global__ __launch_bounds__(256) void k_pre(const float* __restrict__ Ab,
                                             const float* __restrict__ Bb,
                                             const float* __restrict__ xin,
                                             const float* __restrict__ ev,
                                             float* __restrict__ ws) {
  __shared__ float rs[4][64], rq[4][64];
  int blk = blockIdx.x, tid = threadIdx.x;
  if (blk < 771) {
    double* dws = (double*)(ws + WOFF);
    int idx = blk * 256 + tid;
    if (idx < 196608) {
      dws[AD64 + idx] = (double)Ab[idx];
    } else {
      int g = idx - 196608;  // 0..767 (grid sized exactly)
      const int rowoff[3] = {0, 24576, 73728};
      const int kko[3] = {KKOFF0, KKOFF1, KKOFF2};
      int s = g >> 8, i = g & 255;
      float v = Bb[g];
      dws[KKD64 + rowoff[s] + i] = (double)v;
      ws[kko[s] + i] = v;
    }
  } else if (blk < 963) {
    int b2 = blk - 771;  // 0..191
    int b = b2 / 12, part = b2 % 12;
    int j = tid & 63, g = tid >> 6;
    const float* xp = xin + ((size_t)b * 720 + part * 60 + g) * 64 + j;
    float sum = 0.f, ss = 0.f;
#pragma unroll
    for (int i = 0; i < 15; ++i) {
      float v = xp[(size_t)i * 256];
      sum += v; ss += v * v;
    }
    rs[g][j] = sum; rq[g][j] = ss;
    __syncthreads();
    if (g == 0) {
      float s = rs[0][j] + rs[1][j] + rs[2][j] + rs[3][j];
      float q = rq[0][j] + rq[1][j] + rq[2][j] + rq[3][j];
      float* dst = ws + STATSP + ((size_t)b2 * 64 + j) * 2;
      dst[0] = s; dst[1] = q;
    }
  } else if (blk < 987) {
    int idx = (blk - 963) * 256 + tid;
    for (; idx < 36864; idx += 24 * 256) ws[HTOTOFF + idx] = 0.f;
  } else {
    // E pack: ev layout [3][96][256] linear -> packed u32 table
    int idx = (blk - 987) * 256 + tid;  // 0..73727 (288 blocks exactly)
    ((u32*)ws)[EPOFF + idx] = pack_hl(ev[idx]);
  }
}

// ---- fp64 chain GEMM, 32x32 tiles, 2x2 micro, K=N=256, register prefetch ----
struct G64Jobs {
  const double* A[8]; const double* B[8]; double* C[8]; float* CF[8];
  int M[8]; int transB[8]; int tile0[8];
  int njobs;
};

__global__ __launch_bounds__(256) void k_gemm64(G64Jobs jb) {
  int bid = blockIdx.x;
  int j = 0;
  for (int q = 1; q < jb.njobs; ++q) if (bid >= jb.tile0[q]) j = q;
  int local = bid - jb.tile0[j];
  int tm = local >> 3, tn = local & 7;
  const double* A = jb.A[j];
  const double* Bm = jb.B[j];
  double* C = jb.C[j];
  float* CF = jb.CF[j];
  int M = jb.M[j], tB = jb.transB[j];
  int row0 = tm * 32, col0 = tn * 32;
  __shared__ double As[32][33], Bs[32][33];
  int tid = threadIdx.x;
  int ty = tid >> 4, tx = tid & 15;
  int lr = tid >> 3, lk = (tid & 7) << 2;
  double va[4], vb[4];
#pragma unroll
  for (int u = 0; u < 4; ++u) {
    va[u] = (row0 + lr < M) ? A[(size_t)(row0 + lr) * 256 + lk + u] : 0.0;
    vb[u] = tB ? Bm[(size_t)(col0 + lr) * 256 + lk + u]
               : Bm[(size_t)lr * 256 + col0 + lk + u];
  }
  double a00 = 0., a01 = 0., a10 = 0., a11 = 0.;
  for (int kc = 0; kc < 256; kc += 32) {
#pragma unroll
    for (int u = 0; u < 4; ++u) {
      As[lr][lk + u] = va[u];
      if (tB) Bs[lk + u][lr] = vb[u];
      else    Bs[lr][lk + u] = vb[u];
    }
    __syncthreads();
    if (kc < 224) {
      int kn = kc + 32;
#pragma unroll
      for (int u = 0; u < 4; ++u) {
        va[u] = (row0 + lr < M) ? A[(size_t)(row0 + lr) * 256 + kn + lk + u] : 0.0;
        vb[u] = tB ? Bm[(size_t)(col0 + lr) * 256 + kn + lk + u]
                   : Bm[(size_t)(kn + lr) * 256 + col0 + lk + u];
      }
    }
#pragma unroll 8
    for (int k = 0; k < 32; ++k) {
      double x0 = As[2 * ty][k], x1 = As[2 * ty + 1][k];
      double y0 = Bs[k][2 * tx], y1 = Bs[k][2 * tx + 1];
      a00 = fma(x0, y0, a00); a01 = fma(x0, y1, a01);
      a10 = fma(x1, y0, a10); a11 = fma(x1, y1, a11);
    }
    __syncthreads();
  }
  int r0 = row0 + 2 * ty, c0 = col0 + 2 * tx;
  if (r0 < M) {
    C[(size_t)r0 * 256 + c0] = a00; C[(size_t)r0 * 256 + c0 + 1] = a01;
    if (CF) { CF[(size_t)r0 * 256 + c0] = (float)a00; CF[(size_t)r0 * 256 + c0 + 1] = (float)a01; }
  }
  if (r0 + 1 < M) {
    C[(size_t)(r0 + 1) * 256 + c0] = a10; C[(size_t)(r0 + 1) * 256 + c0 + 1] = a11;
    if (CF) { CF[(size_t)(r0 + 1) * 256 + c0] = (float)a10; CF[(size_t)(r0 + 1) * 256 + c0 + 1] = (float)a11; }
  }
}

// ---- S3 (MFMA split-bf16): Wtil[i,x,t] = sum_o w[i,o,x]*E[t,o] ----
// Grid 768 = 6 (s,p) x 128 mb. Block 256 thr = 4 waves.
// BM = 64 rows (2 i-values x 32 x). Wave wid: il = wid&1 (which i),
// kh = wid>>1 (K half: k in [kh*128, kh*128+128)). K chunk = 32 (2 MFMA k-steps).
// A staged per chunk into LDS as packed hi|lo u32, [2 bufs][64 rows][34 pad].
// B (E) read as fragments straight from the packed global table (L2-resident).
// acc = 32x32x16 MFMA x 3 col-frags x 3 products (hh, hl, lh). fp32 K-merge via LDS.
__global__ __launch_bounds__(256) void k_s3(const float* __restrict__ wr,
                                            const float* __restrict__ wi,
                                            float* __restrict__ ws) {
  __shared__ u32 smem[6144];  // 2*2176 u32 staging; reused as 64*96 float merge scratch
  int bid = blockIdx.x;
  int jidx = bid >> 7, mb = bid & 127;
  int s = jidx >> 1, p = jidx & 1;
  const float* w = (p ? wi : wr) + (size_t)s * 2097152;
  const u32* ep = (const u32*)ws + EPOFF + s * 24576;
  float* C = ws + WOFF + (size_t)jidx * 786432 + (size_t)mb * 6144;
  int i0 = mb * 2;
  int tid = threadIdx.x;
  int lane = tid & 63;
  int wid = tid >> 6;
  int il = wid & 1, kh = wid >> 1;

  // staging decode: thread loads 16 consecutive floats of w per iter
  int sh = tid >> 7;           // which K-half buffer this thread fills
  int sil = (tid >> 6) & 1;    // which i
  int so = (tid >> 1) & 31;    // o within chunk
  int sx = (tid & 1) << 4;     // x start (0 or 16)
  const float* wsrc = w + (((size_t)(i0 + sil) * 256 + sh * 128 + so) << 5) + sx;
  u32 sdst = sh * 2176 + (sil * 32 + sx) * 34 + so;

  // compute decode
  int tcol = lane & 31;              // A row (x) / B col (t) / D col
  int og8 = (lane >> 5) << 3;        // k sub-group
  const u32* asrc = smem + kh * 2176 + (il * 32 + tcol) * 34 + og8;
  const u32* bsrc = ep + tcol * 256 + og8;

  f32x16 acc[3];
#pragma unroll
  for (int f = 0; f < 3; ++f)
#pragma unroll
    for (int r = 0; r < 16; ++r) acc[f][r] = 0.f;

  float4 va0 = *(const float4*)(wsrc);
  float4 va1 = *(const float4*)(wsrc + 4);
  float4 va2 = *(const float4*)(wsrc + 8);
  float4 va3 = *(const float4*)(wsrc + 12);

  for (int c = 0; c < 4; ++c) {
    __syncthreads();
    {
      float vv[16] = {va0.x, va0.y, va0.z, va0.w, va1.x, va1.y, va1.z, va1.w,
                      va2.x, va2.y, va2.z, va2.w, va3.x, va3.y, va3.z, va3.w};
#pragma unroll
      for (int u = 0; u < 16; ++u) smem[sdst + u * 34] = pack_hl(vv[u]);
    }
    __syncthreads();
    if (c < 3) {  // register prefetch of next chunk, overlaps MFMA phase
      const float* nsrc = wsrc + (size_t)(c + 1) * 1024;
      va0 = *(const float4*)(nsrc);
      va1 = *(const float4*)(nsrc + 4);
      va2 = *(const float4*)(nsrc + 8);
      va3 = *(const float4*)(nsrc + 12);
    }
    int ko = kh * 128 + c * 32;
#pragma unroll
    for (int ks = 0; ks < 2; ++ks) {
      const uint2* aq = (const uint2*)(asrc + ks * 16);
      uint2 q0 = aq[0], q1 = aq[1], q2 = aq[2], q3 = aq[3];
      u32 ap[8] = {q0.x, q0.y, q1.x, q1.y, q2.x, q2.y, q3.x, q3.y};
      bf16x8 ah, al;
      unpk8(ap, ah, al);
#pragma unroll
      for (int f = 0; f < 3; ++f) {
        const uint4* bq = (const uint4*)(bsrc + f * 8192 + ko + ks * 16);
        uint4 b0 = bq[0], b1 = bq[1];
        u32 bp[8] = {b0.x, b0.y, b0.z, b0.w, b1.x, b1.y, b1.z, b1.w};
        bf16x8 bh, bl;
        unpk8(bp, bh, bl);
        acc[f] = __builtin_amdgcn_mfma_f32_32x32x16_bf16(ah, bh, acc[f], 0, 0, 0);
        acc[f] = __builtin_amdgcn_mfma_f32_32x32x16_bf16(ah, bl, acc[f], 0, 0, 0);
        acc[f] = __builtin_amdgcn_mfma_f32_32x32x16_bf16(al, bh, acc[f], 0, 0, 0);
      }
    }
  }

  // K-split merge (kh=1 partials -> LDS, kh=0 adds and stores)
  __syncthreads();
  float* ms = (float*)smem;
  int crow0 = (lane >> 5) << 2;
  if (kh == 1) {
#pragma unroll
    for (int f = 0; f < 3; ++f)
#pragma unroll
      for (int r = 0; r < 16; ++r) {
        int row = il * 32 + crow0 + (r & 3) + ((r >> 2) << 3);
        ms[row * 96 + f * 32 + tcol] = acc[f][r];
      }
  }
  __syncthreads();
  if (kh == 0) {
#pragma unroll
    for (int f = 0; f < 3; ++f)
#pragma unroll
      for (int r = 0; r < 16; ++r) {
        int row = il * 32 + crow0 + (r & 3) + ((r >> 2) << 3);
        C[row * 96 + f * 32 + tcol] = acc[f][r] + ms[row * 96 + f * 32 + tcol];
      }
  }
}

// ---- S4: R[d,(x,t)] = sum_i KK[d,i]*Wtil[i,(x,t)]   64x64 tiles, K=256 ----
__global__ __launch_bounds__(256) void k_s4(float* __restrict__ ws) {
  int bid = blockIdx.x;
  const int cums[6] = {0, 96, 192, 336, 480, 768};
  int jidx = 0;
  for (int q = 1; q < 6; ++q) if (bid >= cums[q]) jidx = q;
  int local = bid - cums[jidx];
  int s = jidx >> 1, p = jidx & 1;
  const int Ts[3] = {96, 192, 384};
  const int KKo[3] = {KKOFF0, KKOFF1, KKOFF2};
  const int Ro[3] = {R0OFF, R1OFF, R2OFF};
  int T = Ts[s];
  int tm = local / 48, tn = local % 48;
  int row0 = tm * 64, col0 = tn * 64;
  const float* A = ws + KKo[s];
  const float* B = ws + WOFF + (size_t)(2 * s + p) * 786432;
  float* C = ws + Ro[s] + (size_t)p * T * 3072;
  __shared__ float As[32][68], Bs[32][68];  // [k][row], [k][col]
  int tid = threadIdx.x;
  int ty = tid >> 4, tx = tid & 15;
  float acc[4][4];
#pragma unroll
  for (int u = 0; u < 4; ++u)
#pragma unroll
    for (int v = 0; v < 4; ++v) acc[u][v] = 0.f;
  for (int kc = 0; kc < 256; kc += 32) {
    int r = tid >> 2, k8 = (tid & 3) << 3;
    if (row0 + r < T) {
      float4 v0 = *(const float4*)(A + (size_t)(row0 + r) * 256 + kc + k8);
      float4 v1 = *(const float4*)(A + (size_t)(row0 + r) * 256 + kc + k8 + 4);
      As[k8 + 0][r] = v0.x; As[k8 + 1][r] = v0.y; As[k8 + 2][r] = v0.z; As[k8 + 3][r] = v0.w;
      As[k8 + 4][r] = v1.x; As[k8 + 5][r] = v1.y; As[k8 + 6][r] = v1.z; As[k8 + 7][r] = v1.w;
    } else {
#pragma unroll
      for (int u = 0; u < 8; ++u) As[k8 + u][r] = 0.f;
    }
    int kr = tid >> 3, c8 = (tid & 7) << 3;
    const float* bp = B + (size_t)(kc + kr) * 3072 + col0 + c8;
    *(float4*)&Bs[kr][c8] = *(const float4*)bp;
    *(float4*)&Bs[kr][c8 + 4] = *(const float4*)(bp + 4);
    __syncthreads();
#pragma unroll 8
    for (int k = 0; k < 32; ++k) {
      float4 a = *(const float4*)&As[k][ty * 4];
      float4 b = *(const float4*)&Bs[k][tx * 4];
      float aa[4] = {a.x, a.y, a.z, a.w};
      float bb[4] = {b.x, b.y, b.z, b.w};
#pragma unroll
      for (int u = 0; u < 4; ++u)
#pragma unroll
        for (int v = 0; v < 4; ++v) acc[u][v] += aa[u] * bb[v];
    }
    __syncthreads();
  }
#pragma unroll
  for (int u = 0; u < 4; ++u) {
    int rr = row0 + ty * 4 + u;
    if (rr < T) {
      float* cp = C + (size_t)rr * 3072 + col0 + tx * 4;
      *(float4*)cp = make_float4(acc[u][0], acc[u][1], acc[u][2], acc[u][3]);
    }
  }
}

// ---- S5a: prefix-DFT over d + irfft phase, accumulate w_s * val into Htot ----
__global__ __launch_bounds__(192) void k_s5a(const float* __restrict__ mlpw, float* __restrict__ ws) {
  int bid = blockIdx.x;
  int s = bid >> 7;
  int rem = bid & 127;
  int x = rem >> 2;
  int tq = rem & 3;
  const int Ts[3] = {96, 192, 384};
  const int Ro[3] = {R0OFF, R1OFF, R2OFF};
  const int lpbase[3] = {288, 192, 0};
  int T = Ts[s];
  int Lc = T >> 3;
  __shared__ float cs[384][2];
  __shared__ float Lsr[8][24], Lsi[8][24];
  int tid = threadIdx.x;
  for (int e = tid; e < T; e += 192) {
    float th = 6.283185307179586f * (float)e / (float)T;
    cs[e][0] = cosf(th);
    cs[e][1] = sinf(th);
  }
  int c = tid / 24, tl = tid % 24;
  int t = tq * 24 + tl;
  const float* Rre = ws + Ro[s] + (size_t)x * 96 + t;
  const float* Rim = Rre + (size_t)T * 3072;
  float* Htot = ws + HTOTOFF;
  float wsc = mlpw[s];
  __syncthreads();
  int d0 = c * Lc;
  float zr = 0.f, zi = 0.f;
  for (int d = d0; d < d0 + Lc; ++d) {
    float rr = Rre[(size_t)d * 3072];
    float ri = Rim[(size_t)d * 3072];
    int e1 = (x * d) % T;
    float c1 = cs[e1][0], s1 = cs[e1][1];
    zr += c1 * rr + s1 * ri;
    zi += c1 * ri - s1 * rr;
  }
  Lsr[c][tl] = zr; Lsi[c][tl] = zi;
  __syncthreads();
  if (c == 0) {
    float pr = 0.f, pi = 0.f;
#pragma unroll
    for (int cc = 0; cc < 8; ++cc) {
      float lr = Lsr[cc][tl], li = Lsi[cc][tl];
      Lsr[cc][tl] = pr; Lsi[cc][tl] = pi;
      pr += lr; pi += li;
    }
  }
  __syncthreads();
  zr = Lsr[c][tl]; zi = Lsi[c][tl];
  float sc = (((x == 0) ? 1.f : 2.f) / (float)T) * wsc;
  for (int d = d0; d < d0 + Lc; ++d) {
    float rr = Rre[(size_t)d * 3072];
    float ri = Rim[(size_t)d * 3072];
    int e1 = (x * d) % T;
    float c1 = cs[e1][0], s1 = cs[e1][1];
    zr += c1 * rr + s1 * ri;
    zi += c1 * ri - s1 * rr;
    int k = T - 1 - d;
    int e2 = (x * (95 - k)) % T;
    if (e2 < 0) e2 += T;
    float c2 = cs[e2][0], s2 = cs[e2][1];
    atomicAdd(Htot + (size_t)(lpbase[s] + k) * 96 + t, sc * (c2 * zr - s2 * zi));
  }
}

// ---- S6: out[b,t,j] = sum_l x*Htot + mean*(1-S[t]) + std*mlp_b (stats fused) ----
__global__ __launch_bounds__(256) void k_s6(const float* __restrict__ xin, const float* __restrict__ mlpb_p,
                                            const float* __restrict__ ws, float* __restrict__ out) {
  int b = blockIdx.x >> 2, tq = blockIdx.x & 3;
  int tid = threadIdx.x;
  int j = tid & 63, tsub = tid >> 6;
  __shared__ float Ht[384 * 24];
  for (int idx = tid; idx < 384 * 24; idx += 256) {
    int lp = idx / 24, c = idx % 24;
    Ht[idx] = ws[HTOTOFF + lp * 96 + tq * 24 + c];
  }
  float ssum = 0.f, sq = 0.f;
#pragma unroll
  for (int p = 0; p < 12; ++p) {
    const float* src = ws + STATSP + (((size_t)b * 12 + p) * 64 + j) * 2;
    ssum += src[0]; sq += src[1];
  }
  float mn = ssum * (1.f / 720.f);
  float var = sq * (1.f / 720.f) - mn * mn;
  float sd = sqrtf(var + 1e-5f);
  __syncthreads();
  float mlpb = mlpb_p[0];
  float acc[6] = {0.f, 0.f, 0.f, 0.f, 0.f, 0.f};
  float accS[6] = {0.f, 0.f, 0.f, 0.f, 0.f, 0.f};
  const float* xp = xin + ((size_t)b * 720 + 336) * 64 + j;
  for (int lp = 0; lp < 384; ++lp) {
    float xv = xp[(size_t)lp * 64];
    const float* hr = &Ht[lp * 24 + tsub * 6];
    float2 h01 = *(const float2*)&hr[0];
    float2 h23 = *(const float2*)&hr[2];
    float2 h45 = *(const float2*)&hr[4];
    float hh[6] = {h01.x, h01.y, h23.x, h23.y, h45.x, h45.y};
#pragma unroll
    for (int u = 0; u < 6; ++u) {
      acc[u] += xv * hh[u];
      accS[u] += hh[u];
    }
  }
#pragma unroll
  for (int u = 0; u < 6; ++u) {
    int t = tq * 24 + tsub * 6 + u;
    float val = acc[u] + mn * (1.f - accS[u]) + sd * mlpb;
    out[((size_t)b * 96 + t) * 64 + j] = val;
  }
}

extern "C" void kernel_launch(void* const* d_in, const int* in_sizes, int n_in,
                              void* d_out, int out_size, void* d_ws, size_t ws_size,
                              hipStream_t stream) {
  const float* x  = (const float*)d_in[0];
  const float* wr = (const float*)d_in[1];
  const float* wi = (const float*)d_in[2];
  const float* mw = (const float*)d_in[3];
  const float* mb = (const float*)d_in[4];
  const float* Ab = (const float*)d_in[5];
  const float* Bb = (const float*)d_in[6];
  const float* ev = (const float*)d_in[7];
  float* wsf = (float*)d_ws;
  float* out = (float*)d_out;

  k_pre<<<1275, 256, 0, stream>>>(Ab, Bb, x, ev, wsf);

  const double* AD = (const double*)(wsf + WOFF) + AD64;
  double* PD = (double*)(wsf + WOFF) + PD64;
  double* KD = (double*)(wsf + WOFF) + KKD64;
  static const int Ts[3] = {96, 192, 384};
  static const int rowoff[3] = {0, 24576, 73728};
  static const int KKo[3] = {KKOFF0, KKOFF1, KKOFF2};

  // Fused doubling: round r extends KK rows [n, min(2n,T)) = KK[0,n) * P_n^T
  // (dual-written fp64+fp32) and squares P_n -> P_2n in the same launch.
  int have[3] = {1, 1, 1};
  for (int r = 0; r <= 8; ++r) {
    G64Jobs jb;
    jb.njobs = 0;
    int tiles = 0;
    for (int s = 0; s < 3; ++s) {
      int T = Ts[s];
      if (have[s] >= T) continue;
      const double* Pn = (r == 0) ? (AD + (size_t)s * 65536)
                                  : (PD + (size_t)(2 * s + (r & 1)) * 65536);
      int M = ((2 * have[s] < T) ? 2 * have[s] : T) - have[s];
      int q = jb.njobs++;
      jb.A[q] = KD + rowoff[s]; jb.B[q] = Pn;
      jb.C[q] = KD + rowoff[s] + (size_t)have[s] * 256;
      jb.CF[q] = wsf + KKo[s] + (size_t)have[s] * 256;
      jb.M[q] = M; jb.transB[q] = 1; jb.tile0[q] = tiles;
      tiles += ((M + 31) / 32) * 8;
      if (2 * have[s] < T) {
        q = jb.njobs++;
        jb.A[q] = Pn; jb.B[q] = Pn;
        jb.C[q] = PD + (size_t)(2 * s + ((r + 1) & 1)) * 65536;
        jb.CF[q] = nullptr;
        jb.M[q] = 256; jb.transB[q] = 0; jb.tile0[q] = tiles;
        tiles += 64;
      }
      have[s] = (2 * have[s] < T) ? 2 * have[s] : T;
    }
    if (jb.njobs) k_gemm64<<<tiles, 256, 0, stream>>>(jb);
  }

  k_s3<<<768, 256, 0, stream>>>(wr, wi, wsf);
  k_s4<<<1056, 256, 0, stream>>>(wsf);
  k_s5a<<<384, 192, 0, stream>>>(mw, wsf);
  k_s6<<<64, 256, 0, stream>>>(x, mb, wsf, out);
}

// Round 2
// 374.192 us; speedup vs baseline: 1.0547x; 1.0317x over previous
//
#include <hip/hip_runtime.h>

typedef unsigned short u16;
typedef unsigned int u32;

typedef __bf16 bf16x8 __attribute__((ext_vector_type(8)));
typedef unsigned short ushort8 __attribute__((ext_vector_type(8)));
typedef float f32x16 __attribute__((ext_vector_type(16)));

// workspace offsets (in floats)
#define STATSP 2048     // 16*12*64*2 = 24576 floats of stats partials
#define EPOFF 32768     // 3*96*256 = 73728 u32: packed (hi|lo<<16) bf16 of E[s][t][o]
#define KKOFF0 591872
#define KKOFF1 616448
#define KKOFF2 665600
#define WOFF 763904
#define R0OFF 5482496
#define R1OFF 6072320
#define R2OFF 7251968
#define HTOTOFF 11675648
// total = 11712512 floats = ~46.9 MB
// fp64 chain scratch lives INSIDE the Wtil region [WOFF, R0OFF); it is fully
// consumed before k_s3 overwrites Wtil. Offsets in doubles relative to
// (double*)(ws + WOFF):
#define AD64 0        // 3*65536 doubles  (Ad fp64, per scale)
#define PD64 196608   // 6*65536 doubles  (P ping-pong, per scale)
#define KKD64 589824  // 672*256 doubles  (KK rows: s0 96, s1 192, s2 384)
// KK (packed hi/lo u32) lives at KKOFF* ; Wtil2 (packed u32, layout
// [i>>3][n][i&7], n = x*96+t) lives at WOFF + jidx*786432 (u32 view).

// float -> packed u32: low16 = bf16 RNE of a, high16 = bf16 (trunc) of residual
__device__ __forceinline__ u32 pack_hl(float a) {
  u32 bits = __builtin_bit_cast(u32, a);
  u32 hi = (bits + 0x7fffu + ((bits >> 16) & 1u)) >> 16;
  float hif = __builtin_bit_cast(float, hi << 16);
  float r = a - hif;
  u32 lo = __builtin_bit_cast(u32, r) >> 16;
  return hi | (lo << 16);
}

__device__ __forceinline__ void unpk8(const u32* p, bf16x8& h, bf16x8& l) {
  ushort8 hu, lu;
#pragma unroll
  for (int j = 0; j < 8; ++j) {
    u32 v = p[j];
    hu[j] = (unsigned short)(v & 0xffffu);
    lu[j] = (unsigned short)(v >> 16);
  }
  h = __builtin_bit_cast(bf16x8, hu);
  l = __builtin_bit_cast(bf16x8, lu);
}

// ---- k_pre: A->fp64, seed KK row0, stats1, zero Htot, pack E hi/lo ----
__global__ __launch_bounds__(256) void k_pre(const float* __restrict__ Ab,
                                             const float* __restrict__ Bb,
                                             const float* __restrict__ xin,
                                             const float* __restrict__ ev,
                                             float* __restrict__ ws) {
  __shared__ float rs[4][64], rq[4][64];
  int blk = blockIdx.x, tid = threadIdx.x;
  if (blk < 771) {
    double* dws = (double*)(ws + WOFF);
    int idx = blk * 256 + tid;
    if (idx < 196608) {
      dws[AD64 + idx] = (double)Ab[idx];
    } else {
      int g = idx - 196608;  // 0..767 (grid sized exactly)
      const int rowoff[3] = {0, 24576, 73728};
      const int kko[3] = {KKOFF0, KKOFF1, KKOFF2};
      int s = g >> 8, i = g & 255;
      float v = Bb[g];
      dws[KKD64 + rowoff[s] + i] = (double)v;
      ((u32*)ws)[kko[s] + i] = pack_hl(v);
    }
  } else if (blk < 963) {
    int b2 = blk - 771;  // 0..191
    int b = b2 / 12, part = b2 % 12;
    int j = tid & 63, g = tid >> 6;
    const float* xp = xin + ((size_t)b * 720 + part * 60 + g) * 64 + j;
    float sum = 0.f, ss = 0.f;
#pragma unroll
    for (int i = 0; i < 15; ++i) {
      float v = xp[(size_t)i * 256];
      sum += v; ss += v * v;
    }
    rs[g][j] = sum; rq[g][j] = ss;
    __syncthreads();
    if (g == 0) {
      float s = rs[0][j] + rs[1][j] + rs[2][j] + rs[3][j];
      float q = rq[0][j] + rq[1][j] + rq[2][j] + rq[3][j];
      float* dst = ws + STATSP + ((size_t)b2 * 64 + j) * 2;
      dst[0] = s; dst[1] = q;
    }
  } else if (blk < 987) {
    int idx = (blk - 963) * 256 + tid;
    for (; idx < 36864; idx += 24 * 256) ws[HTOTOFF + idx] = 0.f;
  } else {
    // E pack: ev layout [3][96][256] linear -> packed u32 table
    int idx = (blk - 987) * 256 + tid;  // 0..73727 (288 blocks exactly)
    ((u32*)ws)[EPOFF + idx] = pack_hl(ev[idx]);
  }
}

// ---- fp64 chain GEMM, 32x32 tiles, 2x2 micro, K=N=256, register prefetch ----
struct G64Jobs {
  const double* A[8]; const double* B[8]; double* C[8]; float* CF[8];
  int M[8]; int transB[8]; int tile0[8];
  int njobs;
};

__global__ __launch_bounds__(256) void k_gemm64(G64Jobs jb) {
  int bid = blockIdx.x;
  int j = 0;
  for (int q = 1; q < jb.njobs; ++q) if (bid >= jb.tile0[q]) j = q;
  int local = bid - jb.tile0[j];
  int tm = local >> 3, tn = local & 7;
  const double* A = jb.A[j];
  const double* Bm = jb.B[j];
  double* C = jb.C[j];
  float* CF = jb.CF[j];
  int M = jb.M[j], tB = jb.transB[j];
  int row0 = tm * 32, col0 = tn * 32;
  __shared__ double As[32][33], Bs[32][33];
  int tid = threadIdx.x;
  int ty = tid >> 4, tx = tid & 15;
  int lr = tid >> 3, lk = (tid & 7) << 2;
  double va[4], vb[4];
#pragma unroll
  for (int u = 0; u < 4; ++u) {
    va[u] = (row0 + lr < M) ? A[(size_t)(row0 + lr) * 256 + lk + u] : 0.0;
    vb[u] = tB ? Bm[(size_t)(col0 + lr) * 256 + lk + u]
               : Bm[(size_t)lr * 256 + col0 + lk + u];
  }
  double a00 = 0., a01 = 0., a10 = 0., a11 = 0.;
  for (int kc = 0; kc < 256; kc += 32) {
#pragma unroll
    for (int u = 0; u < 4; ++u) {
      As[lr][lk + u] = va[u];
      if (tB) Bs[lk + u][lr] = vb[u];
      else    Bs[lr][lk + u] = vb[u];
    }
    __syncthreads();
    if (kc < 224) {
      int kn = kc + 32;
#pragma unroll
      for (int u = 0; u < 4; ++u) {
        va[u] = (row0 + lr < M) ? A[(size_t)(row0 + lr) * 256 + kn + lk + u] : 0.0;
        vb[u] = tB ? Bm[(size_t)(col0 + lr) * 256 + kn + lk + u]
                   : Bm[(size_t)(kn + lr) * 256 + col0 + lk + u];
      }
    }
#pragma unroll 8
    for (int k = 0; k < 32; ++k) {
      double x0 = As[2 * ty][k], x1 = As[2 * ty + 1][k];
      double y0 = Bs[k][2 * tx], y1 = Bs[k][2 * tx + 1];
      a00 = fma(x0, y0, a00); a01 = fma(x0, y1, a01);
      a10 = fma(x1, y0, a10); a11 = fma(x1, y1, a11);
    }
    __syncthreads();
  }
  int r0 = row0 + 2 * ty, c0 = col0 + 2 * tx;
  if (r0 < M) {
    C[(size_t)r0 * 256 + c0] = a00; C[(size_t)r0 * 256 + c0 + 1] = a01;
    if (CF) {
      ((u32*)CF)[(size_t)r0 * 256 + c0] = pack_hl((float)a00);
      ((u32*)CF)[(size_t)r0 * 256 + c0 + 1] = pack_hl((float)a01);
    }
  }
  if (r0 + 1 < M) {
    C[(size_t)(r0 + 1) * 256 + c0] = a10; C[(size_t)(r0 + 1) * 256 + c0 + 1] = a11;
    if (CF) {
      ((u32*)CF)[(size_t)(r0 + 1) * 256 + c0] = pack_hl((float)a10);
      ((u32*)CF)[(size_t)(r0 + 1) * 256 + c0 + 1] = pack_hl((float)a11);
    }
  }
}

// ---- S3 (MFMA split-bf16): Wtil[i,x,t] = sum_o w[i,o,x]*E[t,o] ----
// Output written PACKED (hi|lo u32) in layout Wtil2[i>>3][n][i&7], n=x*96+t,
// so k_s4 can read k-contiguous B fragments directly from global.
// mb is XCD-swizzled so the 4 blocks sharing each 64B output sector land on
// the same XCD (L2 write-combining of the partial-sector uint2 stores).
__global__ __launch_bounds__(256) void k_s3(const float* __restrict__ wr,
                                            const float* __restrict__ wi,
                                            float* __restrict__ ws) {
  __shared__ u32 smem[6400];  // staging 2*2176 u32; epilogue merge 64*97 f32
  int bid = blockIdx.x;
  int jidx = bid >> 7;
  int r127 = bid & 127;
  int mb = ((r127 & 7) << 4) | (r127 >> 3);  // XCD-group swizzle (bijective)
  int s = jidx >> 1, p = jidx & 1;
  const float* w = (p ? wi : wr) + (size_t)s * 2097152;
  const u32* ep = (const u32*)ws + EPOFF + s * 24576;
  int i0 = mb * 2;
  int tid = threadIdx.x;
  int lane = tid & 63;
  int wid = tid >> 6;
  int il = wid & 1, kh = wid >> 1;

  // staging decode: thread loads 16 consecutive floats of w per iter
  int sh = tid >> 7;           // which K-half buffer this thread fills
  int sil = (tid >> 6) & 1;    // which i
  int so = (tid >> 1) & 31;    // o within chunk
  int sx = (tid & 1) << 4;     // x start (0 or 16)
  const float* wsrc = w + (((size_t)(i0 + sil) * 256 + sh * 128 + so) << 5) + sx;
  u32 sdst = sh * 2176 + (sil * 32 + sx) * 34 + so;

  // compute decode
  int tcol = lane & 31;              // A row (x) / B col (t) / D col
  int og8 = (lane >> 5) << 3;        // k sub-group
  const u32* asrc = smem + kh * 2176 + (il * 32 + tcol) * 34 + og8;
  const u32* bsrc = ep + tcol * 256 + og8;

  f32x16 acc[3];
#pragma unroll
  for (int f = 0; f < 3; ++f)
#pragma unroll
    for (int r = 0; r < 16; ++r) acc[f][r] = 0.f;

  float4 va0 = *(const float4*)(wsrc);
  float4 va1 = *(const float4*)(wsrc + 4);
  float4 va2 = *(const float4*)(wsrc + 8);
  float4 va3 = *(const float4*)(wsrc + 12);

  for (int c = 0; c < 4; ++c) {
    __syncthreads();
    {
      float vv[16] = {va0.x, va0.y, va0.z, va0.w, va1.x, va1.y, va1.z, va1.w,
                      va2.x, va2.y, va2.z, va2.w, va3.x, va3.y, va3.z, va3.w};
#pragma unroll
      for (int u = 0; u < 16; ++u) smem[sdst + u * 34] = pack_hl(vv[u]);
    }
    __syncthreads();
    if (c < 3) {  // register prefetch of next chunk, overlaps MFMA phase
      const float* nsrc = wsrc + (size_t)(c + 1) * 1024;
      va0 = *(const float4*)(nsrc);
      va1 = *(const float4*)(nsrc + 4);
      va2 = *(const float4*)(nsrc + 8);
      va3 = *(const float4*)(nsrc + 12);
    }
    int ko = kh * 128 + c * 32;
#pragma unroll
    for (int ks = 0; ks < 2; ++ks) {
      const uint2* aq = (const uint2*)(asrc + ks * 16);
      uint2 q0 = aq[0], q1 = aq[1], q2 = aq[2], q3 = aq[3];
      u32 ap[8] = {q0.x, q0.y, q1.x, q1.y, q2.x, q2.y, q3.x, q3.y};
      bf16x8 ah, al;
      unpk8(ap, ah, al);
#pragma unroll
      for (int f = 0; f < 3; ++f) {
        const uint4* bq = (const uint4*)(bsrc + f * 8192 + ko + ks * 16);
        uint4 b0 = bq[0], b1 = bq[1];
        u32 bp[8] = {b0.x, b0.y, b0.z, b0.w, b1.x, b1.y, b1.z, b1.w};
        bf16x8 bh, bl;
        unpk8(bp, bh, bl);
        acc[f] = __builtin_amdgcn_mfma_f32_32x32x16_bf16(ah, bh, acc[f], 0, 0, 0);
        acc[f] = __builtin_amdgcn_mfma_f32_32x32x16_bf16(ah, bl, acc[f], 0, 0, 0);
        acc[f] = __builtin_amdgcn_mfma_f32_32x32x16_bf16(al, bh, acc[f], 0, 0, 0);
      }
    }
  }

  // Merge K halves in LDS (stride 97 = conflict-free), then pack + store.
  __syncthreads();
  float* ms = (float*)smem;
  int crow0 = (lane >> 5) << 2;
  if (kh == 1) {
#pragma unroll
    for (int f = 0; f < 3; ++f)
#pragma unroll
      for (int r = 0; r < 16; ++r) {
        int row = il * 32 + crow0 + (r & 3) + ((r >> 2) << 3);
        ms[row * 97 + f * 32 + tcol] = acc[f][r];
      }
  }
  __syncthreads();
  if (kh == 0) {
#pragma unroll
    for (int f = 0; f < 3; ++f)
#pragma unroll
      for (int r = 0; r < 16; ++r) {
        int row = il * 32 + crow0 + (r & 3) + ((r >> 2) << 3);
        int a = row * 97 + f * 32 + tcol;
        ms[a] += acc[f][r];
      }
  }
  __syncthreads();
  // pack both i-values per n, store uint2 into Wtil2[g][n][io]
  u32* W2 = (u32*)(ws + WOFF) + (size_t)jidx * 786432 + (size_t)(mb >> 2) * 24576 +
            ((mb & 3) << 1);
  int x = tid & 31, cg = tid >> 5;
#pragma unroll
  for (int j = 0; j < 12; ++j) {
    int c = cg * 12 + j;
    float v0 = ms[x * 97 + c];
    float v1 = ms[(32 + x) * 97 + c];
    uint2 st;
    st.x = pack_hl(v0);
    st.y = pack_hl(v1);
    *(uint2*)(W2 + (size_t)(x * 96 + c) * 8) = st;
  }
}

// ---- S4 (MFMA split-bf16, zero-LDS): R[d,n] = sum_i KK[d,i]*Wtil[i,n] ----
// A = packed KK [T][256] (k-contiguous), B = Wtil2 [i>>3][n][i&7]
// (k-contiguous within each 8-group). Both fragments are direct 32B global
// reads (L2-resident). Block = 32 d x 256 n, 4 waves (one 64-n slice each).
__global__ __launch_bounds__(256) void k_s4(float* __restrict__ ws) {
  int bid = blockIdx.x;
  const int cums[6] = {0, 36, 72, 144, 216, 360};  // tiles: (T/32)*12 per (s,p)
  int jidx = 0;
#pragma unroll
  for (int q = 1; q < 6; ++q) if (bid >= cums[q]) jidx = q;
  int local = bid - cums[jidx];
  int s = jidx >> 1, p = jidx & 1;
  const int Ts[3] = {96, 192, 384};
  const int KKo[3] = {KKOFF0, KKOFF1, KKOFF2};
  const int Ro[3] = {R0OFF, R1OFF, R2OFF};
  int T = Ts[s];
  int td = local / 12, tn = local % 12;
  int d0 = td * 32;
  int tid = threadIdx.x;
  int lane = tid & 63, wid = tid >> 6;
  int n0 = tn * 256 + wid * 64;
  int l31 = lane & 31, kg = lane >> 5;
  const u32* Ap = (const u32*)ws + KKo[s] + (size_t)(d0 + l31) * 256 + kg * 8;
  const u32* Bp = (const u32*)ws + WOFF + (size_t)jidx * 786432 + (size_t)kg * 24576;
  const u32* b0p = Bp + (size_t)(n0 + l31) * 8;
  const u32* b1p = Bp + (size_t)(n0 + 32 + l31) * 8;
  float* C = ws + Ro[s] + (size_t)p * T * 3072;

  f32x16 acc0, acc1;
#pragma unroll
  for (int r = 0; r < 16; ++r) { acc0[r] = 0.f; acc1[r] = 0.f; }

#pragma unroll 2
  for (int ks = 0; ks < 16; ++ks) {
    uint4 a0 = *(const uint4*)(Ap + ks * 16);
    uint4 a1 = *(const uint4*)(Ap + ks * 16 + 4);
    size_t bo = (size_t)ks * 49152;  // 2 groups of 8 i per kstep
    uint4 x0 = *(const uint4*)(b0p + bo);
    uint4 x1 = *(const uint4*)(b0p + bo + 4);
    uint4 y0 = *(const uint4*)(b1p + bo);
    uint4 y1 = *(const uint4*)(b1p + bo + 4);
    u32 ap[8] = {a0.x, a0.y, a0.z, a0.w, a1.x, a1.y, a1.z, a1.w};
    bf16x8 ah, al;
    unpk8(ap, ah, al);
    {
      u32 bp[8] = {x0.x, x0.y, x0.z, x0.w, x1.x, x1.y, x1.z, x1.w};
      bf16x8 bh, bl;
      unpk8(bp, bh, bl);
      acc0 = __builtin_amdgcn_mfma_f32_32x32x16_bf16(ah, bh, acc0, 0, 0, 0);
      acc0 = __builtin_amdgcn_mfma_f32_32x32x16_bf16(ah, bl, acc0, 0, 0, 0);
      acc0 = __builtin_amdgcn_mfma_f32_32x32x16_bf16(al, bh, acc0, 0, 0, 0);
      acc0 = __builtin_amdgcn_mfma_f32_32x32x16_bf16(al, bl, acc0, 0, 0, 0);
    }
    {
      u32 bp[8] = {y0.x, y0.y, y0.z, y0.w, y1.x, y1.y, y1.z, y1.w};
      bf16x8 bh, bl;
      unpk8(bp, bh, bl);
      acc1 = __builtin_amdgcn_mfma_f32_32x32x16_bf16(ah, bh, acc1, 0, 0, 0);
      acc1 = __builtin_amdgcn_mfma_f32_32x32x16_bf16(ah, bl, acc1, 0, 0, 0);
      acc1 = __builtin_amdgcn_mfma_f32_32x32x16_bf16(al, bh, acc1, 0, 0, 0);
      acc1 = __builtin_amdgcn_mfma_f32_32x32x16_bf16(al, bl, acc1, 0, 0, 0);
    }
  }

  int crow = kg << 2;
#pragma unroll
  for (int r = 0; r < 16; ++r) {
    int row = d0 + crow + (r & 3) + ((r >> 2) << 3);
    C[(size_t)row * 3072 + n0 + l31] = acc0[r];
    C[(size_t)row * 3072 + n0 + 32 + l31] = acc1[r];
  }
}

// ---- S5a: prefix-DFT over d + irfft phase, accumulate w_s * val into Htot ----
__global__ __launch_bounds__(192) void k_s5a(const float* __restrict__ mlpw, float* __restrict__ ws) {
  int bid = blockIdx.x;
  int s = bid >> 7;
  int rem = bid & 127;
  int x = rem >> 2;
  int tq = rem & 3;
  const int Ts[3] = {96, 192, 384};
  const int Ro[3] = {R0OFF, R1OFF, R2OFF};
  const int lpbase[3] = {288, 192, 0};
  int T = Ts[s];
  int Lc = T >> 3;
  __shared__ float cs[384][2];
  __shared__ float Lsr[8][24], Lsi[8][24];
  int tid = threadIdx.x;
  for (int e = tid; e < T; e += 192) {
    float th = 6.283185307179586f * (float)e / (float)T;
    cs[e][0] = cosf(th);
    cs[e][1] = sinf(th);
  }
  int c = tid / 24, tl = tid % 24;
  int t = tq * 24 + tl;
  const float* Rre = ws + Ro[s] + (size_t)x * 96 + t;
  const float* Rim = Rre + (size_t)T * 3072;
  float* Htot = ws + HTOTOFF;
  float wsc = mlpw[s];
  __syncthreads();
  int d0 = c * Lc;
  float zr = 0.f, zi = 0.f;
  for (int d = d0; d < d0 + Lc; ++d) {
    float rr = Rre[(size_t)d * 3072];
    float ri = Rim[(size_t)d * 3072];
    int e1 = (x * d) % T;
    float c1 = cs[e1][0], s1 = cs[e1][1];
    zr += c1 * rr + s1 * ri;
    zi += c1 * ri - s1 * rr;
  }
  Lsr[c][tl] = zr; Lsi[c][tl] = zi;
  __syncthreads();
  if (c == 0) {
    float pr = 0.f, pi = 0.f;
#pragma unroll
    for (int cc = 0; cc < 8; ++cc) {
      float lr = Lsr[cc][tl], li = Lsi[cc][tl];
      Lsr[cc][tl] = pr; Lsi[cc][tl] = pi;
      pr += lr; pi += li;
    }
  }
  __syncthreads();
  zr = Lsr[c][tl]; zi = Lsi[c][tl];
  float sc = (((x == 0) ? 1.f : 2.f) / (float)T) * wsc;
  for (int d = d0; d < d0 + Lc; ++d) {
    float rr = Rre[(size_t)d * 3072];
    float ri = Rim[(size_t)d * 3072];
    int e1 = (x * d) % T;
    float c1 = cs[e1][0], s1 = cs[e1][1];
    zr += c1 * rr + s1 * ri;
    zi += c1 * ri - s1 * rr;
    int k = T - 1 - d;
    int e2 = (x * (95 - k)) % T;
    if (e2 < 0) e2 += T;
    float c2 = cs[e2][0], s2 = cs[e2][1];
    atomicAdd(Htot + (size_t)(lpbase[s] + k) * 96 + t, sc * (c2 * zr - s2 * zi));
  }
}

// ---- S6: out[b,t,j] = sum_l x*Htot + mean*(1-S[t]) + std*mlp_b (stats fused) ----
__global__ __launch_bounds__(256) void k_s6(const float* __restrict__ xin, const float* __restrict__ mlpb_p,
                                            const float* __restrict__ ws, float* __restrict__ out) {
  int b = blockIdx.x >> 2, tq = blockIdx.x & 3;
  int tid = threadIdx.x;
  int j = tid & 63, tsub = tid >> 6;
  __shared__ float Ht[384 * 24];
  for (int idx = tid; idx < 384 * 24; idx += 256) {
    int lp = idx / 24, c = idx % 24;
    Ht[idx] = ws[HTOTOFF + lp * 96 + tq * 24 + c];
  }
  float ssum = 0.f, sq = 0.f;
#pragma unroll
  for (int p = 0; p < 12; ++p) {
    const float* src = ws + STATSP + (((size_t)b * 12 + p) * 64 + j) * 2;
    ssum += src[0]; sq += src[1];
  }
  float mn = ssum * (1.f / 720.f);
  float var = sq * (1.f / 720.f) - mn * mn;
  float sd = sqrtf(var + 1e-5f);
  __syncthreads();
  float mlpb = mlpb_p[0];
  float acc[6] = {0.f, 0.f, 0.f, 0.f, 0.f, 0.f};
  float accS[6] = {0.f, 0.f, 0.f, 0.f, 0.f, 0.f};
  const float* xp = xin + ((size_t)b * 720 + 336) * 64 + j;
  for (int lp = 0; lp < 384; ++lp) {
    float xv = xp[(size_t)lp * 64];
    const float* hr = &Ht[lp * 24 + tsub * 6];
    float2 h01 = *(const float2*)&hr[0];
    float2 h23 = *(const float2*)&hr[2];
    float2 h45 = *(const float2*)&hr[4];
    float hh[6] = {h01.x, h01.y, h23.x, h23.y, h45.x, h45.y};
#pragma unroll
    for (int u = 0; u < 6; ++u) {
      acc[u] += xv * hh[u];
      accS[u] += hh[u];
    }
  }
#pragma unroll
  for (int u = 0; u < 6; ++u) {
    int t = tq * 24 + tsub * 6 + u;
    float val = acc[u] + mn * (1.f - accS[u]) + sd * mlpb;
    out[((size_t)b * 96 + t) * 64 + j] = val;
  }
}

extern "C" void kernel_launch(void* const* d_in, const int* in_sizes, int n_in,
                              void* d_out, int out_size, void* d_ws, size_t ws_size,
                              hipStream_t stream) {
  const float* x  = (const float*)d_in[0];
  const float* wr = (const float*)d_in[1];
  const float* wi = (const float*)d_in[2];
  const float* mw = (const float*)d_in[3];
  const float* mb = (const float*)d_in[4];
  const float* Ab = (const float*)d_in[5];
  const float* Bb = (const float*)d_in[6];
  const float* ev = (const float*)d_in[7];
  float* wsf = (float*)d_ws;
  float* out = (float*)d_out;

  k_pre<<<1275, 256, 0, stream>>>(Ab, Bb, x, ev, wsf);

  const double* AD = (const double*)(wsf + WOFF) + AD64;
  double* PD = (double*)(wsf + WOFF) + PD64;
  double* KD = (double*)(wsf + WOFF) + KKD64;
  static const int Ts[3] = {96, 192, 384};
  static const int rowoff[3] = {0, 24576, 73728};
  static const int KKo[3] = {KKOFF0, KKOFF1, KKOFF2};

  // Fused doubling: round r extends KK rows [n, min(2n,T)) = KK[0,n) * P_n^T
  // (dual-written fp64 + packed-bf16) and squares P_n -> P_2n in the same launch.
  int have[3] = {1, 1, 1};
  for (int r = 0; r <= 8; ++r) {
    G64Jobs jb;
    jb.njobs = 0;
    int tiles = 0;
    for (int s = 0; s < 3; ++s) {
      int T = Ts[s];
      if (have[s] >= T) continue;
      const double* Pn = (r == 0) ? (AD + (size_t)s * 65536)
                                  : (PD + (size_t)(2 * s + (r & 1)) * 65536);
      int M = ((2 * have[s] < T) ? 2 * have[s] : T) - have[s];
      int q = jb.njobs++;
      jb.A[q] = KD + rowoff[s]; jb.B[q] = Pn;
      jb.C[q] = KD + rowoff[s] + (size_t)have[s] * 256;
      jb.CF[q] = wsf + KKo[s] + (size_t)have[s] * 256;
      jb.M[q] = M; jb.transB[q] = 1; jb.tile0[q] = tiles;
      tiles += ((M + 31) / 32) * 8;
      if (2 * have[s] < T) {
        q = jb.njobs++;
        jb.A[q] = Pn; jb.B[q] = Pn;
        jb.C[q] = PD + (size_t)(2 * s + ((r + 1) & 1)) * 65536;
        jb.CF[q] = nullptr;
        jb.M[q] = 256; jb.transB[q] = 0; jb.tile0[q] = tiles;
        tiles += 64;
      }
      have[s] = (2 * have[s] < T) ? 2 * have[s] : T;
    }
    if (jb.njobs) k_gemm64<<<tiles, 256, 0, stream>>>(jb);
  }

  k_s3<<<768, 256, 0, stream>>>(wr, wi, wsf);
  k_s4<<<504, 256, 0, stream>>>(wsf);
  k_s5a<<<384, 192, 0, stream>>>(mw, wsf);
  k_s6<<<64, 256, 0, stream>>>(x, mb, wsf, out);
}